// Round 20
// baseline (93.458 us; speedup 1.0000x reference)
//
#include <hip/hip_runtime.h>
#include <math.h>

// ---- problem geometry ----
#define T_IN    8192
#define T1      8183        // conv1 'valid' output length
#define LP      4087        // after MaxPool1d(2)
#define NFLAT   523136      // 128 * 4087
#define NFLAT4  130784      // NFLAT / 4
#define NDIM    10000
#define RSTRIDE 8208        // padded row stride for r1
#define PROW    8192        // pacc row stride
#define PA_OFF  (64*RSTRIDE)            // pacc: [2][128][PROW]
#define F_OFF   (PA_OFF + 2*128*PROW)   // flat[NFLAT]
#define P_OFF   (F_OFF + NFLAT)         // partials[128][32]
#define W_OFF   (P_OFF + 8192)          // warm-kernel scratch
#define NCHUNK  32
#define CHUNK4  4087        // float4 per chunk

typedef __attribute__((ext_vector_type(4))) float f4;
typedef __attribute__((ext_vector_type(2))) float f2;

// =====================================================================
// Kernel 1: conv1 (round-11 exact; ~2 us)
// =====================================================================
__global__ __launch_bounds__(256) void k1_conv1(
    const float* __restrict__ sig, const float* __restrict__ w1,
    const float* __restrict__ b1, float* __restrict__ r1)
{
  __shared__ float4 srow[266];
  const int tid = threadIdx.x;
  const int t0b = blockIdx.x * 256;
  for (int idx = tid; idx < 266; idx += 256) {
    int t = t0b + idx;
    float4 v = make_float4(0.f, 0.f, 0.f, 0.f);
    if (t < T_IN) v = ((const float4*)sig)[t];
    srow[idx] = v;
  }
  __syncthreads();
  const int t = t0b + tid;
  float s[40];
#pragma unroll
  for (int k = 0; k < 10; ++k) {
    float4 v = srow[tid + k];
    s[4*k+0] = v.x; s[4*k+1] = v.y; s[4*k+2] = v.z; s[4*k+3] = v.w;
  }
  const int c0 = blockIdx.y * 8;
  for (int c = c0; c < c0 + 8; ++c) {
    const float* __restrict__ w = w1 + c * 40;
    float a0 = 0.f, a1 = 0.f, a2 = 0.f, a3 = 0.f;
#pragma unroll
    for (int k = 0; k < 10; ++k) {
      a0 = fmaf(s[4*k+0], w[k     ], a0);
      a1 = fmaf(s[4*k+1], w[10 + k], a1);
      a2 = fmaf(s[4*k+2], w[20 + k], a2);
      a3 = fmaf(s[4*k+3], w[30 + k], a3);
    }
    float v = fmaxf((a0 + a1) + (a2 + a3) + b1[c], 0.f);
    if (t < T1) r1[c * RSTRIDE + t] = v;
  }
}

// =====================================================================
// Kernel W: L2-warmer for r1 (2.1 MB) AND w2 (320 KB).
// 512 blocks; per XCD (round-robin i%8), its 64 blocks sweep slices
// (i>>3)&31 of both buffers -> every XCD L2 holds all of r1+w2 before
// k2a. The w2 warm is the round-20 addition: k2a's cold stall is
// attributed to its 128 serialized s_load chains missing K$->MALL
// (~500cy each ~= the 29 us excess); vector-warming w2 into L2 cuts
// the miss service to ~130cy without touching k2a's code. Perf
// heuristic only; sums written to dead scratch keep loads live.
// =====================================================================
__global__ __launch_bounds__(256) void k_warm(
    const float* __restrict__ r1, const float* __restrict__ w2,
    float* __restrict__ scratch)
{
  const int tid   = threadIdx.x;
  const int slice = (blockIdx.x >> 3) & 31;
  const f4* __restrict__ base = (const f4*)r1 + (size_t)slice * 4096;
  f4 s = (f4)0.f;
#pragma unroll
  for (int i = 0; i < 16; ++i) {
    f4 v = base[tid + i * 256];
    s.x += v.x; s.y += v.y; s.z += v.z; s.w += v.w;
  }
  // w2: 81920 floats = 20480 f4; slice = 640 f4 (2.5 KB)
  const f4* __restrict__ wb = (const f4*)w2 + (size_t)slice * 640;
  for (int i = tid; i < 640; i += 256) {
    f4 v = wb[i];
    s.x += v.x; s.y += v.y; s.z += v.z; s.w += v.w;
  }
  scratch[blockIdx.x * 256 + tid] = (s.x + s.y) + (s.z + s.w);
}

// =====================================================================
// Kernel 2a: conv2 partials, c-split x2, s_load weights (round-15 exact)
// =====================================================================
__global__ __launch_bounds__(256) void k2a_conv2part(
    const float* __restrict__ r1, const float* __restrict__ w2,
    float* __restrict__ pacc)
{
  const int tid  = threadIdx.x;
  const int lane = tid & 63;
  const int wave = tid >> 6;
  const int t0b  = blockIdx.x * 256;
  const int o0   = __builtin_amdgcn_readfirstlane(blockIdx.y * 8 + wave * 2);
  const int h    = blockIdx.z;             // c-half
  const int cb   = h * 32;

  float acc[2][4];
#pragma unroll
  for (int a = 0; a < 2; ++a)
#pragma unroll
    for (int q = 0; q < 4; ++q) acc[a][q] = 0.f;

#pragma unroll 2
  for (int ci = 0; ci < 32; ++ci) {
    const int c = cb + ci;
    const f4* __restrict__ p = (const f4*)(r1 + c * RSTRIDE + t0b) + lane;
    f4 v0 = p[0];          // floats t0 .. t0+3   (consecutive lanes coalesced)
    f4 v1 = p[1];
    f4 v2 = p[2];
    f4 v3 = p[3];          // f[13..15] dead; stays inside padded row
    float f[16];
    f[0]=v0.x; f[1]=v0.y; f[2]=v0.z; f[3]=v0.w;
    f[4]=v1.x; f[5]=v1.y; f[6]=v1.z; f[7]=v1.w;
    f[8]=v2.x; f[9]=v2.y; f[10]=v2.z; f[11]=v2.w;
    f[12]=v3.x; f[13]=v3.y; f[14]=v3.z; f[15]=v3.w;
#pragma unroll
    for (int oo = 0; oo < 2; ++oo) {
      const float* __restrict__ w = w2 + ((o0 + oo) * 64 + c) * 10; // wave-uniform s_loads
#pragma unroll
      for (int k = 0; k < 10; ++k) {
        float wv = w[k];
#pragma unroll
        for (int tt = 0; tt < 4; ++tt)
          acc[oo][tt] = fmaf(wv, f[k + tt], acc[oo][tt]);
      }
    }
  }

#pragma unroll
  for (int oo = 0; oo < 2; ++oo) {
    f4 v; v.x = acc[oo][0]; v.y = acc[oo][1]; v.z = acc[oo][2]; v.w = acc[oo][3];
    *(f4*)(pacc + (size_t)(h * 128 + o0 + oo) * PROW + t0b + lane * 4) = v;
  }
}

// =====================================================================
// Kernel 2b: combine halves + bias + relu + pool -> flat (round-15 exact)
// =====================================================================
__global__ __launch_bounds__(256) void k2b_combine(
    const float* __restrict__ pacc, const float* __restrict__ b2,
    float* __restrict__ flat)
{
  const unsigned gtid = blockIdx.x * 256u + threadIdx.x;
#pragma unroll
  for (int e = 0; e < 2; ++e) {
    const unsigned idx = gtid + e * 262144u;
    if (idx < NFLAT) {
      const unsigned o = idx / (unsigned)LP;     // magic-mul div
      const unsigned l = idx - o * (unsigned)LP;
      const unsigned t = 2u * l;
      f2 x0 = *(const f2*)(pacc + (size_t)o * PROW + t);
      f2 x1 = *(const f2*)(pacc + (size_t)(128 + o) * PROW + t);
      const float bias = b2[o];
      float aa = (x0.x + x1.x) + bias;
      float bb = (x0.y + x1.y) + bias;
      flat[idx] = fmaxf(fmaxf(aa, bb), 0.f);     // relu-then-pool == pool-then-relu
    }
  }
}

// =====================================================================
// Kernel 3: linear, plain loads (round-11 exact; 37.5 us ~= 268 MB at
// the ~7.1 TB/s delivered ceiling measured across every variant)
// =====================================================================
__global__ __launch_bounds__(256) void k3_linear(
    const float* __restrict__ lw, const float* __restrict__ flat,
    float* __restrict__ partials)
{
  const int tid = threadIdx.x;
  const int ch  = blockIdx.x;
  const int j0  = blockIdx.y * 4;
  const f4* __restrict__ fl = (const f4*)flat + (size_t)ch * CHUNK4;

  float r[4];
#pragma unroll
  for (int ph = 0; ph < 2; ++ph) {
    const int j = j0 + 2 * ph;
    const f4* __restrict__ p0 = (const f4*)lw + (size_t)(j + 0) * NFLAT4 + (size_t)ch * CHUNK4;
    const f4* __restrict__ p1 = (const f4*)lw + (size_t)(j + 1) * NFLAT4 + (size_t)ch * CHUNK4;
    f4 a0 = (f4)0.f, a1 = (f4)0.f;
    for (int i = tid; i < CHUNK4; i += 256) {
      f4 x  = fl[i];
      f4 w0 = p0[i];
      f4 w1 = p1[i];
      a0.x = fmaf(x.x, w0.x, a0.x); a0.y = fmaf(x.y, w0.y, a0.y);
      a0.z = fmaf(x.z, w0.z, a0.z); a0.w = fmaf(x.w, w0.w, a0.w);
      a1.x = fmaf(x.x, w1.x, a1.x); a1.y = fmaf(x.y, w1.y, a1.y);
      a1.z = fmaf(x.z, w1.z, a1.z); a1.w = fmaf(x.w, w1.w, a1.w);
    }
    r[2*ph + 0] = (a0.x + a0.y) + (a0.z + a0.w);
    r[2*ph + 1] = (a1.x + a1.y) + (a1.z + a1.w);
  }

  __shared__ float red[4][257];
#pragma unroll
  for (int j = 0; j < 4; ++j) red[j][tid] = r[j];
  for (int off = 128; off > 0; off >>= 1) {
    __syncthreads();
    if (tid < off) {
#pragma unroll
      for (int j = 0; j < 4; ++j) red[j][tid] += red[j][tid + off];
    }
  }
  if (tid == 0) {
#pragma unroll
    for (int j = 0; j < 4; ++j) partials[(j0 + j) * NCHUNK + ch] = red[j][0];
  }
}

// =====================================================================
// Kernel 4: finalize (round-11 exact; ~3.7 us)
// =====================================================================
__global__ __launch_bounds__(64) void k4_hdc(
    const float* __restrict__ partials, const float* __restrict__ lin_b,
    const float* __restrict__ hdc_w, const float* __restrict__ hdc_b,
    const float* __restrict__ feat, const int* __restrict__ feat_idx,
    const float* __restrict__ feat_w, const float* __restrict__ feat_b,
    float* __restrict__ out)
{
  __shared__ __align__(16) float y[128];
  __shared__ float fv[18];
  const int tid = threadIdx.x;
#pragma unroll
  for (int half = 0; half < 2; ++half) {
    const int row = tid + half * 64;
    float s = lin_b[row];
    const float* p = partials + row * NCHUNK;
#pragma unroll
    for (int c = 0; c < NCHUNK; ++c) s += p[c];
    y[row] = fmaxf(s, 0.f);
  }
  if (tid < 18) fv[tid] = feat[feat_idx[tid]];
  __syncthreads();

  const int d = blockIdx.x * 64 + tid;
  if (d >= NDIM) return;

  const float4* __restrict__ hw = (const float4*)(hdc_w + d * 128);
  const float4* __restrict__ yy = (const float4*)y;
  float4 ac = make_float4(0, 0, 0, 0);
#pragma unroll
  for (int q = 0; q < 32; ++q) {
    float4 w = hw[q];
    float4 v = yy[q];
    ac.x = fmaf(w.x, v.x, ac.x); ac.y = fmaf(w.y, v.y, ac.y);
    ac.z = fmaf(w.z, v.z, ac.z); ac.w = fmaf(w.w, v.w, ac.w);
  }
  const float proj = (ac.x + ac.y) + (ac.z + ac.w);
  const float sample_hv = cosf(proj + hdc_b[d]) * sinf(proj);

  float h[18];
#pragma unroll
  for (int i = 0; i < 18; ++i) {
    float fp = fv[i] * feat_w[i * NDIM + d];
    h[i] = cosf(fp + feat_b[i * NDIM + d]) * sinf(fp);
  }
  const float feat_hv =
      (h[14] + h[11]) * h[16]
    * (h[4] + h[8] + h[6] + h[1] + h[5] + h[12] + h[17])
    * h[13] * (h[15] + h[2]) * h[3]
    * h[0] * h[10] * h[7] * h[9];

  const float comb = sample_hv + feat_hv;
  out[d] = comb > 0.f ? 1.f : -1.f;
}

// =====================================================================
extern "C" void kernel_launch(void* const* d_in, const int* in_sizes, int n_in,
                              void* d_out, int out_size, void* d_ws, size_t ws_size,
                              hipStream_t stream)
{
  const float* sig  = (const float*)d_in[0];
  const float* feat = (const float*)d_in[1];
  const float* w1   = (const float*)d_in[2];
  const float* b1   = (const float*)d_in[3];
  const float* w2   = (const float*)d_in[4];
  const float* b2   = (const float*)d_in[5];
  const float* lw   = (const float*)d_in[6];
  const float* lb   = (const float*)d_in[7];
  const float* hw   = (const float*)d_in[8];
  const float* hb   = (const float*)d_in[9];
  const float* fw   = (const float*)d_in[10];
  const float* fb   = (const float*)d_in[11];
  const int*   fidx = (const int*)d_in[12];
  float* out = (float*)d_out;
  float* ws  = (float*)d_ws;

  float* r1       = ws;              // [64][RSTRIDE]
  float* pacc     = ws + PA_OFF;     // [2][128][PROW]
  float* flat     = ws + F_OFF;      // [NFLAT]
  float* partials = ws + P_OFF;      // [128][NCHUNK]
  float* wscratch = ws + W_OFF;      // warm-kernel sink

  k1_conv1     <<<dim3(32, 8),     256, 0, stream>>>(sig, w1, b1, r1);
  k_warm       <<<dim3(512),       256, 0, stream>>>(r1, w2, wscratch);
  k2a_conv2part<<<dim3(32, 16, 2), 256, 0, stream>>>(r1, w2, pacc);
  k2b_combine  <<<dim3(1024),      256, 0, stream>>>(pacc, b2, flat);
  k3_linear    <<<dim3(32, 32),    256, 0, stream>>>(lw, flat, partials);
  k4_hdc       <<<dim3(157, 1),    64,  0, stream>>>(partials, lb, hw, hb,
                                                     feat, fidx, fw, fb, out);
}

// Round 21
// 89.788 us; speedup vs baseline: 1.0409x; 1.0409x over previous
//
#include <hip/hip_runtime.h>
#include <math.h>

// ---- problem geometry ----
#define T_IN    8192
#define T1      8183        // conv1 'valid' output length
#define LP      4087        // after MaxPool1d(2)
#define NFLAT   523136      // 128 * 4087
#define NFLAT4  130784      // NFLAT / 4
#define NDIM    10000
#define RSTRIDE 8208        // padded row stride for r1
#define PROW    8192        // pacc row stride
#define PA_OFF  (64*RSTRIDE)            // pacc: [2][128][PROW]
#define F_OFF   (PA_OFF + 2*128*PROW)   // flat[NFLAT]
#define P_OFF   (F_OFF + NFLAT)         // partials[128][32]
#define NCHUNK  32
#define CHUNK4  4087        // float4 per chunk

typedef __attribute__((ext_vector_type(4))) float f4;
typedef __attribute__((ext_vector_type(2))) float f2;

// =====================================================================
// Kernel 1: conv1 (~2 us, measured round-7 probe)
// =====================================================================
__global__ __launch_bounds__(256) void k1_conv1(
    const float* __restrict__ sig, const float* __restrict__ w1,
    const float* __restrict__ b1, float* __restrict__ r1)
{
  __shared__ float4 srow[266];
  const int tid = threadIdx.x;
  const int t0b = blockIdx.x * 256;
  for (int idx = tid; idx < 266; idx += 256) {
    int t = t0b + idx;
    float4 v = make_float4(0.f, 0.f, 0.f, 0.f);
    if (t < T_IN) v = ((const float4*)sig)[t];
    srow[idx] = v;
  }
  __syncthreads();
  const int t = t0b + tid;
  float s[40];
#pragma unroll
  for (int k = 0; k < 10; ++k) {
    float4 v = srow[tid + k];
    s[4*k+0] = v.x; s[4*k+1] = v.y; s[4*k+2] = v.z; s[4*k+3] = v.w;
  }
  const int c0 = blockIdx.y * 8;
  for (int c = c0; c < c0 + 8; ++c) {
    const float* __restrict__ w = w1 + c * 40;
    float a0 = 0.f, a1 = 0.f, a2 = 0.f, a3 = 0.f;
#pragma unroll
    for (int k = 0; k < 10; ++k) {
      a0 = fmaf(s[4*k+0], w[k     ], a0);
      a1 = fmaf(s[4*k+1], w[10 + k], a1);
      a2 = fmaf(s[4*k+2], w[20 + k], a2);
      a3 = fmaf(s[4*k+3], w[30 + k], a3);
    }
    float v = fmaxf((a0 + a1) + (a2 + a3) + b1[c], 0.f);
    if (t < T1) r1[c * RSTRIDE + t] = v;
  }
}

// =====================================================================
// Kernel 2a: conv2 partials, c-split x2, LDS-free, s_load weights.
// Best-measured config (round 15, 88.3 us pipeline). Refuted variants:
// LDS-staged tile (bank conflicts, 1.6e8), LDS weights (+4.4), c-split
// x4 (+5.5), 1ch/wave (+10), L2 pre-warming r1 and/or w2 (null).
// =====================================================================
__global__ __launch_bounds__(256) void k2a_conv2part(
    const float* __restrict__ r1, const float* __restrict__ w2,
    float* __restrict__ pacc)
{
  const int tid  = threadIdx.x;
  const int lane = tid & 63;
  const int wave = tid >> 6;
  const int t0b  = blockIdx.x * 256;
  const int o0   = __builtin_amdgcn_readfirstlane(blockIdx.y * 8 + wave * 2);
  const int h    = blockIdx.z;             // c-half
  const int cb   = h * 32;

  float acc[2][4];
#pragma unroll
  for (int a = 0; a < 2; ++a)
#pragma unroll
    for (int q = 0; q < 4; ++q) acc[a][q] = 0.f;

#pragma unroll 2
  for (int ci = 0; ci < 32; ++ci) {
    const int c = cb + ci;
    const f4* __restrict__ p = (const f4*)(r1 + c * RSTRIDE + t0b) + lane;
    f4 v0 = p[0];          // floats t0 .. t0+3   (consecutive lanes coalesced)
    f4 v1 = p[1];
    f4 v2 = p[2];
    f4 v3 = p[3];          // f[13..15] dead; stays inside padded row
    float f[16];
    f[0]=v0.x; f[1]=v0.y; f[2]=v0.z; f[3]=v0.w;
    f[4]=v1.x; f[5]=v1.y; f[6]=v1.z; f[7]=v1.w;
    f[8]=v2.x; f[9]=v2.y; f[10]=v2.z; f[11]=v2.w;
    f[12]=v3.x; f[13]=v3.y; f[14]=v3.z; f[15]=v3.w;
#pragma unroll
    for (int oo = 0; oo < 2; ++oo) {
      const float* __restrict__ w = w2 + ((o0 + oo) * 64 + c) * 10; // wave-uniform s_loads
#pragma unroll
      for (int k = 0; k < 10; ++k) {
        float wv = w[k];
#pragma unroll
        for (int tt = 0; tt < 4; ++tt)
          acc[oo][tt] = fmaf(wv, f[k + tt], acc[oo][tt]);
      }
    }
  }

#pragma unroll
  for (int oo = 0; oo < 2; ++oo) {
    f4 v; v.x = acc[oo][0]; v.y = acc[oo][1]; v.z = acc[oo][2]; v.w = acc[oo][3];
    *(f4*)(pacc + (size_t)(h * 128 + o0 + oo) * PROW + t0b + lane * 4) = v;
  }
}

// =====================================================================
// Kernel 2b: combine halves + bias + relu + pool -> flat (~2.5 us)
// =====================================================================
__global__ __launch_bounds__(256) void k2b_combine(
    const float* __restrict__ pacc, const float* __restrict__ b2,
    float* __restrict__ flat)
{
  const unsigned gtid = blockIdx.x * 256u + threadIdx.x;
#pragma unroll
  for (int e = 0; e < 2; ++e) {
    const unsigned idx = gtid + e * 262144u;
    if (idx < NFLAT) {
      const unsigned o = idx / (unsigned)LP;     // magic-mul div
      const unsigned l = idx - o * (unsigned)LP;
      const unsigned t = 2u * l;
      f2 x0 = *(const f2*)(pacc + (size_t)o * PROW + t);
      f2 x1 = *(const f2*)(pacc + (size_t)(128 + o) * PROW + t);
      const float bias = b2[o];
      float aa = (x0.x + x1.x) + bias;
      float bb = (x0.y + x1.y) + bias;
      flat[idx] = fmaxf(fmaxf(aa, bb), 0.f);     // relu-then-pool == pool-then-relu
    }
  }
}

// =====================================================================
// Kernel 3: linear, plain loads. 37.5-40 us = 268 MB at the ~7.1 TB/s
// delivered fabric ceiling (same ceiling the harness fill kernels hit);
// MALL is flushed between replays by the 1 GB ws-poison fills, so no
// cross-replay residency exists. NT variants neutral-to-worse (refuted).
// =====================================================================
__global__ __launch_bounds__(256) void k3_linear(
    const float* __restrict__ lw, const float* __restrict__ flat,
    float* __restrict__ partials)
{
  const int tid = threadIdx.x;
  const int ch  = blockIdx.x;
  const int j0  = blockIdx.y * 4;
  const f4* __restrict__ fl = (const f4*)flat + (size_t)ch * CHUNK4;

  float r[4];
#pragma unroll
  for (int ph = 0; ph < 2; ++ph) {
    const int j = j0 + 2 * ph;
    const f4* __restrict__ p0 = (const f4*)lw + (size_t)(j + 0) * NFLAT4 + (size_t)ch * CHUNK4;
    const f4* __restrict__ p1 = (const f4*)lw + (size_t)(j + 1) * NFLAT4 + (size_t)ch * CHUNK4;
    f4 a0 = (f4)0.f, a1 = (f4)0.f;
    for (int i = tid; i < CHUNK4; i += 256) {
      f4 x  = fl[i];
      f4 w0 = p0[i];
      f4 w1 = p1[i];
      a0.x = fmaf(x.x, w0.x, a0.x); a0.y = fmaf(x.y, w0.y, a0.y);
      a0.z = fmaf(x.z, w0.z, a0.z); a0.w = fmaf(x.w, w0.w, a0.w);
      a1.x = fmaf(x.x, w1.x, a1.x); a1.y = fmaf(x.y, w1.y, a1.y);
      a1.z = fmaf(x.z, w1.z, a1.z); a1.w = fmaf(x.w, w1.w, a1.w);
    }
    r[2*ph + 0] = (a0.x + a0.y) + (a0.z + a0.w);
    r[2*ph + 1] = (a1.x + a1.y) + (a1.z + a1.w);
  }

  __shared__ float red[4][257];
#pragma unroll
  for (int j = 0; j < 4; ++j) red[j][tid] = r[j];
  for (int off = 128; off > 0; off >>= 1) {
    __syncthreads();
    if (tid < off) {
#pragma unroll
      for (int j = 0; j < 4; ++j) red[j][tid] += red[j][tid + off];
    }
  }
  if (tid == 0) {
#pragma unroll
    for (int j = 0; j < 4; ++j) partials[(j0 + j) * NCHUNK + ch] = red[j][0];
  }
}

// =====================================================================
// Kernel 4: finalize (~3.7 us, measured round-7 probe)
// =====================================================================
__global__ __launch_bounds__(64) void k4_hdc(
    const float* __restrict__ partials, const float* __restrict__ lin_b,
    const float* __restrict__ hdc_w, const float* __restrict__ hdc_b,
    const float* __restrict__ feat, const int* __restrict__ feat_idx,
    const float* __restrict__ feat_w, const float* __restrict__ feat_b,
    float* __restrict__ out)
{
  __shared__ __align__(16) float y[128];
  __shared__ float fv[18];
  const int tid = threadIdx.x;
#pragma unroll
  for (int half = 0; half < 2; ++half) {
    const int row = tid + half * 64;
    float s = lin_b[row];
    const float* p = partials + row * NCHUNK;
#pragma unroll
    for (int c = 0; c < NCHUNK; ++c) s += p[c];
    y[row] = fmaxf(s, 0.f);
  }
  if (tid < 18) fv[tid] = feat[feat_idx[tid]];
  __syncthreads();

  const int d = blockIdx.x * 64 + tid;
  if (d >= NDIM) return;

  const float4* __restrict__ hw = (const float4*)(hdc_w + d * 128);
  const float4* __restrict__ yy = (const float4*)y;
  float4 ac = make_float4(0, 0, 0, 0);
#pragma unroll
  for (int q = 0; q < 32; ++q) {
    float4 w = hw[q];
    float4 v = yy[q];
    ac.x = fmaf(w.x, v.x, ac.x); ac.y = fmaf(w.y, v.y, ac.y);
    ac.z = fmaf(w.z, v.z, ac.z); ac.w = fmaf(w.w, v.w, ac.w);
  }
  const float proj = (ac.x + ac.y) + (ac.z + ac.w);
  const float sample_hv = cosf(proj + hdc_b[d]) * sinf(proj);

  float h[18];
#pragma unroll
  for (int i = 0; i < 18; ++i) {
    float fp = fv[i] * feat_w[i * NDIM + d];
    h[i] = cosf(fp + feat_b[i * NDIM + d]) * sinf(fp);
  }
  const float feat_hv =
      (h[14] + h[11]) * h[16]
    * (h[4] + h[8] + h[6] + h[1] + h[5] + h[12] + h[17])
    * h[13] * (h[15] + h[2]) * h[3]
    * h[0] * h[10] * h[7] * h[9];

  const float comb = sample_hv + feat_hv;
  out[d] = comb > 0.f ? 1.f : -1.f;
}

// =====================================================================
extern "C" void kernel_launch(void* const* d_in, const int* in_sizes, int n_in,
                              void* d_out, int out_size, void* d_ws, size_t ws_size,
                              hipStream_t stream)
{
  const float* sig  = (const float*)d_in[0];
  const float* feat = (const float*)d_in[1];
  const float* w1   = (const float*)d_in[2];
  const float* b1   = (const float*)d_in[3];
  const float* w2   = (const float*)d_in[4];
  const float* b2   = (const float*)d_in[5];
  const float* lw   = (const float*)d_in[6];
  const float* lb   = (const float*)d_in[7];
  const float* hw   = (const float*)d_in[8];
  const float* hb   = (const float*)d_in[9];
  const float* fw   = (const float*)d_in[10];
  const float* fb   = (const float*)d_in[11];
  const int*   fidx = (const int*)d_in[12];
  float* out = (float*)d_out;
  float* ws  = (float*)d_ws;

  float* r1       = ws;              // [64][RSTRIDE]
  float* pacc     = ws + PA_OFF;     // [2][128][PROW]
  float* flat     = ws + F_OFF;      // [NFLAT]
  float* partials = ws + P_OFF;      // [128][NCHUNK]

  k1_conv1     <<<dim3(32, 8),     256, 0, stream>>>(sig, w1, b1, r1);
  k2a_conv2part<<<dim3(32, 16, 2), 256, 0, stream>>>(r1, w2, pacc);
  k2b_combine  <<<dim3(1024),      256, 0, stream>>>(pacc, b2, flat);
  k3_linear    <<<dim3(32, 32),    256, 0, stream>>>(lw, flat, partials);
  k4_hdc       <<<dim3(157, 1),    64,  0, stream>>>(partials, lb, hw, hb,
                                                     feat, fidx, fw, fb, out);
}